// Round 7
// baseline (290.597 us; speedup 1.0000x reference)
//
#include <hip/hip_runtime.h>

// AtlasAttention v5 — barrier-free wave-private fused MLP, no atomics.
// out = MLP2(relu(MLP1(poly(clip(X@Wq)))))[:, :64], heads folded.
//   setup: cast X->bf16; transpose Wq / W1[64:] / W2[:, :64] to [n][k] bf16;
//          b1' = b1 + c0*colsum(W1[:64])   (constant poly feature folded out, K:256->192)
//   gemm1: Qb = bf16(Xb @ Wqb^T)           (m97-style, 64x128 tile)
//   fused: wave-private: each wave owns 16 q-rows. poly -> LDS Ps[16][192];
//          4 chunks of 128 h-cols: stage1 (W1t frags from L2, no LDS staging),
//          relu -> LDS Hs[16][128], stage2 accumulates out[16][64].
//          NO __syncthreads, NO atomics, H never in global memory.
// Clamp(+-1e6) elided: |x|<=10, coeffs=1/i! => |c3 x^3| <= 167 << 1e6 (never binds).
//
// ws layout (bytes):
//   Xb  @ 0          : 8192*768*2  = 12,582,912
//   Wqb @ 12,582,912 : 768*768*2   =  1,179,648   [n][k]
//   W1t @ 13,762,560 : 512*192*2   =    196,608   [n][k], k = (oct-1)*64+d, oct 1..3
//   W2t @ 13,959,168 : 64*512*2    =     65,536   [n][k], first 64 cols of W2
//   b1p @ 14,024,704 : 512*4       =      2,048
//   Qb  @ 14,026,752 : 98304*64*2  = 12,582,912

typedef unsigned short u16;
typedef __attribute__((ext_vector_type(8))) short short8;
typedef __attribute__((ext_vector_type(8))) u16 u16x8;
typedef __attribute__((ext_vector_type(4))) float f32x4;
typedef __attribute__((ext_vector_type(4))) u16 u16x4;

__device__ __forceinline__ u16 f2bf(float f) {
    unsigned u = __builtin_bit_cast(unsigned, f);
    u += 0x7FFFu + ((u >> 16) & 1u);   // RNE
    return (u16)(u >> 16);
}
__device__ __forceinline__ float bf2f(u16 h) {
    return __builtin_bit_cast(float, (unsigned)h << 16);
}
__device__ __forceinline__ void gl2lds16(const void* g, void* l) {
    __builtin_amdgcn_global_load_lds(
        (const __attribute__((address_space(1))) unsigned int*)g,
        (__attribute__((address_space(3))) unsigned int*)l, 16, 0, 0);
}

// ---------------- setup kernels ----------------

__global__ __launch_bounds__(256) void cast_f32_bf16(const float* __restrict__ in,
                                                     u16* __restrict__ out, int n4) {
    int i = blockIdx.x * 256 + threadIdx.x;
    if (i < n4) {
        float4 v = reinterpret_cast<const float4*>(in)[i];
        u16x4 o = {f2bf(v.x), f2bf(v.y), f2bf(v.z), f2bf(v.w)};
        reinterpret_cast<u16x4*>(out)[i] = o;
    }
}

// in: [R][Cin] fp32; out: [C][R] bf16. grid (C/32, R/32), block (32,8).
__global__ __launch_bounds__(256) void transpose_cast(const float* __restrict__ in,
                                                      u16* __restrict__ out,
                                                      int R, int Cin) {
    __shared__ float t[32][33];
    const int c0 = blockIdx.x * 32, r0 = blockIdx.y * 32;
    const int tx = threadIdx.x, ty = threadIdx.y;
    #pragma unroll
    for (int j = 0; j < 32; j += 8)
        t[ty + j][tx] = in[(size_t)(r0 + ty + j) * Cin + c0 + tx];
    __syncthreads();
    #pragma unroll
    for (int j = 0; j < 32; j += 8)
        out[(size_t)(c0 + ty + j) * R + r0 + tx] = f2bf(t[tx][ty + j]);
}

// b1p[n] = b1[n] + c0 * sum_{d<64} W1[d][n].  grid 2 x 256.
__global__ __launch_bounds__(256) void b1fold(const float* __restrict__ W1,
                                              const float* __restrict__ b1,
                                              const float* __restrict__ coeffs,
                                              float* __restrict__ b1p) {
    int n = blockIdx.x * 256 + threadIdx.x;
    float s = 0.f;
    #pragma unroll 8
    for (int d = 0; d < 64; ++d) s += W1[d * 512 + n];
    b1p[n] = b1[n] + coeffs[0] * s;
}

// ---------------- GEMM1: Qb = bf16(Xb @ Wqb^T), m97-style ----------------
// BM=64 BN=128, 4 waves of 32x64 tiles, grid (128, 6).

__global__ __launch_bounds__(256)
void gemm1(const u16* __restrict__ A, const u16* __restrict__ B,
           u16* __restrict__ C)
{
    constexpr int BM = 64, BN = 128, K = 768, LD = 768;
    __shared__ u16 As[BM * 32];
    __shared__ u16 Bs[BN * 32];

    const int tid = threadIdx.x;
    const int w = tid >> 6, lane = tid & 63;
    const int lrow = lane >> 2, lslot = lane & 3;
    const int m16 = lane & 15, quad = lane >> 4;
    const int bm = blockIdx.x * BM, bn = blockIdx.y * BN;
    const int wr = (w & 1) * 32, wc = (w >> 1) * 64;

    f32x4 acc[2][4];
    #pragma unroll
    for (int i = 0; i < 2; ++i)
        #pragma unroll
        for (int j = 0; j < 4; ++j)
            acc[i][j] = (f32x4){0.f, 0.f, 0.f, 0.f};

    for (int k0 = 0; k0 < K; k0 += 32) {
        #pragma unroll
        for (int i = 0; i < 2; ++i) {
            const int row = (w * 2 + i) * 16 + lrow;
            const int c = lslot ^ ((row >> 2) & 3);
            gl2lds16(B + (size_t)(bn + row) * LD + k0 + c * 8,
                     &Bs[row * 32 + lslot * 8]);
        }
        {
            const int row = w * 16 + lrow;
            const int c = lslot ^ ((row >> 2) & 3);
            gl2lds16(A + (size_t)(bm + row) * LD + k0 + c * 8,
                     &As[row * 32 + lslot * 8]);
        }
        __syncthreads();

        short8 af[2], bfr[4];
        #pragma unroll
        for (int i = 0; i < 2; ++i) {
            const int r = wr + i * 16 + m16;
            const int s = quad ^ ((r >> 2) & 3);
            af[i] = *reinterpret_cast<const short8*>(&As[r * 32 + s * 8]);
        }
        #pragma unroll
        for (int j = 0; j < 4; ++j) {
            const int r = wc + j * 16 + m16;
            const int s = quad ^ ((r >> 2) & 3);
            bfr[j] = *reinterpret_cast<const short8*>(&Bs[r * 32 + s * 8]);
        }
        #pragma unroll
        for (int i = 0; i < 2; ++i)
            #pragma unroll
            for (int j = 0; j < 4; ++j)
                acc[i][j] = __builtin_amdgcn_mfma_f32_16x16x32_bf16(
                    af[i], bfr[j], acc[i][j], 0, 0, 0);
        __syncthreads();
    }

    #pragma unroll
    for (int j = 0; j < 4; ++j) {
        const int col = bn + wc + j * 16 + m16;
        #pragma unroll
        for (int i = 0; i < 2; ++i)
            #pragma unroll
            for (int r = 0; r < 4; ++r) {
                const int row = bm + wr + i * 16 + quad * 4 + r;
                C[(size_t)row * LD + col] = f2bf(acc[i][j][r]);
            }
    }
}

// ---------------- fused MLP v5: barrier-free, wave-private ----------------
// grid (1536). Block = 64 rows, 4 waves; wave owns 16 rows.
// Per wave LDS (5376 u16 = 10.75 KB): Ps[16][192] stride 200 (poly features,
// bf16), Hs[16][128] stride 136. Padded strides (200/136) shift each row by
// 4 banks -> all b128 accesses <=2-way bank-aliased (free, m136).
// Correctness of same-wave LDS handoff (write lanes != read lanes): DS ops
// from one wave execute in order; wave_barrier() pins compiler program order;
// the reads' own lgkmcnt waits imply the earlier writes completed.

__global__ __launch_bounds__(256, 3)
void fused_mlp(const u16* __restrict__ Qb,      // [98304][64] bf16
               const u16* __restrict__ W1t,     // [512][192] bf16
               const float* __restrict__ b1p,   // [512]
               const u16* __restrict__ W2t,     // [64][512] bf16
               const float* __restrict__ b2,    // [256] (first 64 used)
               const float* __restrict__ coeffs,
               float* __restrict__ out)         // [98304][64] fp32
{
    __shared__ u16 lds[4 * 5376];               // 43 KB
    const int tid = threadIdx.x;
    const int w = tid >> 6, lane = tid & 63;
    const int m16 = lane & 15, quad = lane >> 4;
    u16* Ps = lds + w * 5376;                   // [16][192] stride 200
    u16* Hs = Ps + 3200;                        // [16][128] stride 136
    const long base = (long)blockIdx.x * 64 + w * 16;

    const float c1 = coeffs[1], c2 = coeffs[2], c3 = coeffs[3];

    // ---- phase A: poly-expand this wave's 16 q-rows into Ps ----
    #pragma unroll
    for (int i = 0; i < 2; ++i) {
        const int idx = i * 64 + lane;
        const int r = idx >> 3, dc = idx & 7;   // row 0..15, d-chunk 0..7
        const u16x8 qv = *reinterpret_cast<const u16x8*>(
            Qb + (base + r) * 64 + dc * 8);
        short8 p1, p2, p3;
        #pragma unroll
        for (int e = 0; e < 8; ++e) {
            const float x = fminf(fmaxf(bf2f(qv[e]), -10.f), 10.f);
            const float x2 = x * x;
            p1[e] = (short)f2bf(c1 * x);
            p2[e] = (short)f2bf(c2 * x2);
            p3[e] = (short)f2bf(c3 * x2 * x);
        }
        *reinterpret_cast<short8*>(&Ps[r * 200 + dc * 8])       = p1;  // k =   0+d
        *reinterpret_cast<short8*>(&Ps[r * 200 + 64 + dc * 8])  = p2;  // k =  64+d
        *reinterpret_cast<short8*>(&Ps[r * 200 + 128 + dc * 8]) = p3;  // k = 128+d
    }
    __builtin_amdgcn_wave_barrier();

    f32x4 acc2[4];
    #pragma unroll
    for (int j = 0; j < 4; ++j) acc2[j] = (f32x4){0.f, 0.f, 0.f, 0.f};

    #pragma unroll 1
    for (int nc = 0; nc < 4; ++nc) {
        const int bn0 = nc * 128;

        // bias prefetch (independent, issued early)
        float bv[8];
        #pragma unroll
        for (int j = 0; j < 8; ++j) bv[j] = b1p[bn0 + j * 16 + m16];

        // ---- stage 1: Hchunk[16][128] = Ps @ W1t[bn0:bn0+128]^T, K=192 ----
        f32x4 acc1[8];
        #pragma unroll
        for (int j = 0; j < 8; ++j) acc1[j] = (f32x4){0.f, 0.f, 0.f, 0.f};

        #pragma unroll
        for (int ks = 0; ks < 6; ++ks) {
            const short8 af = *reinterpret_cast<const short8*>(
                &Ps[m16 * 200 + (ks * 4 + quad) * 8]);
            short8 bfv[8];
            #pragma unroll
            for (int j = 0; j < 8; ++j)
                bfv[j] = *reinterpret_cast<const short8*>(
                    W1t + (size_t)(bn0 + j * 16 + m16) * 192 + ks * 32 + quad * 8);
            #pragma unroll
            for (int j = 0; j < 8; ++j)
                acc1[j] = __builtin_amdgcn_mfma_f32_16x16x32_bf16(
                    af, bfv[j], acc1[j], 0, 0, 0);
        }

        // ---- relu + bf16 -> Hs (C-layout scalar stores, 2-way banks) ----
        #pragma unroll
        for (int j = 0; j < 8; ++j) {
            const int nl = j * 16 + m16;
            #pragma unroll
            for (int rr = 0; rr < 4; ++rr) {
                const int rl = quad * 4 + rr;
                Hs[rl * 136 + nl] = f2bf(fmaxf(acc1[j][rr] + bv[j], 0.f));
            }
        }
        __builtin_amdgcn_wave_barrier();

        // ---- stage 2: acc2 += Hchunk @ W2t[:, bn0:bn0+128]^T ----
        #pragma unroll
        for (int kk = 0; kk < 4; ++kk) {
            const short8 hf = *reinterpret_cast<const short8*>(
                &Hs[m16 * 136 + (kk * 4 + quad) * 8]);
            #pragma unroll
            for (int j = 0; j < 4; ++j) {
                const short8 wv = *reinterpret_cast<const short8*>(
                    W2t + (size_t)(j * 16 + m16) * 512 + bn0 + kk * 32 + quad * 8);
                acc2[j] = __builtin_amdgcn_mfma_f32_16x16x32_bf16(
                    hf, wv, acc2[j], 0, 0, 0);
            }
        }
        __builtin_amdgcn_wave_barrier();   // Hs reused next chunk
    }

    // ---- epilogue: out[16][64] for this wave's rows ----
    #pragma unroll
    for (int j = 0; j < 4; ++j) {
        const int col = j * 16 + m16;
        const float b2v = b2[col];
        #pragma unroll
        for (int rr = 0; rr < 4; ++rr)
            out[(base + quad * 4 + rr) * 64 + col] = acc2[j][rr] + b2v;
    }
}

// ---------------- host ----------------

extern "C" void kernel_launch(void* const* d_in, const int* in_sizes, int n_in,
                              void* d_out, int out_size, void* d_ws, size_t ws_size,
                              hipStream_t stream) {
    const float* X      = (const float*)d_in[0];
    const float* Wq     = (const float*)d_in[1];
    const float* coeffs = (const float*)d_in[2];
    const float* W1     = (const float*)d_in[3];
    const float* b1     = (const float*)d_in[4];
    const float* W2     = (const float*)d_in[5];
    const float* b2     = (const float*)d_in[6];
    float* out = (float*)d_out;

    char* ws = (char*)d_ws;
    u16*   Xb  = (u16*)(ws);
    u16*   Wqb = (u16*)(ws + 12582912);
    u16*   W1t = (u16*)(ws + 13762560);
    u16*   W2t = (u16*)(ws + 13959168);
    float* b1p = (float*)(ws + 14024704);
    u16*   Qb  = (u16*)(ws + 14026752);

    cast_f32_bf16<<<6144, 256, 0, stream>>>(X, Xb, 8192 * 768 / 4);
    transpose_cast<<<dim3(24, 24), dim3(32, 8), 0, stream>>>(Wq, Wqb, 768, 768);
    // W1 rows 64..255 (oct 1..3) -> W1t [512][192]
    transpose_cast<<<dim3(16, 6),  dim3(32, 8), 0, stream>>>(W1 + 64 * 512, W1t, 192, 512);
    // W2 first 64 cols -> W2t [64][512]
    transpose_cast<<<dim3(2, 16),  dim3(32, 8), 0, stream>>>(W2, W2t, 512, 256);
    b1fold<<<2, 256, 0, stream>>>(W1, b1, coeffs, b1p);

    gemm1<<<dim3(128, 6), 256, 0, stream>>>(Xb, Wqb, Qb);
    fused_mlp<<<1536, 256, 0, stream>>>(Qb, W1t, b1p, W2t, b2, coeffs, out);
}